// Round 14
// baseline (95.047 us; speedup 1.0000x reference)
//
#include <hip/hip_runtime.h>
#include <stdint.h>

#define IN_F 4096
#define OUT_F 11008
#define M_ROWS 256
#define RANK 16
#define NWORDS 256           // packed words per T row

#define BM 128
#define BN 128
#define BK 64
#define KSPLIT 4
#define K_PER 1024
#define NIT 16               // K_PER / BK

typedef unsigned short u16;
typedef __attribute__((ext_vector_type(8))) short short8;
typedef __attribute__((ext_vector_type(4))) float floatx4;

__device__ __forceinline__ u16 f32_to_bf16_rne(float f) {
    uint32_t u = __builtin_bit_cast(uint32_t, f);
    uint32_t r = (u + 0x7FFFu + ((u >> 16) & 1u)) >> 16;
    return (u16)r;
}

// ---------------- prep: rowsum, lora_xA, x->bf16 (VERIFIED) ----------------
__global__ __launch_bounds__(256) void prep_kernel(
    const float* __restrict__ x, const float* __restrict__ lora_A,
    u16* __restrict__ xb, float* __restrict__ srow, float* __restrict__ lxa)
{
    const int m = blockIdx.x;
    const int tid = threadIdx.x;
    const float4* xrow4 = (const float4*)(x + (size_t)m * IN_F);
    const float4* la4 = (const float4*)lora_A;
    float ssum = 0.f;
    float acc[RANK];
#pragma unroll
    for (int r = 0; r < RANK; ++r) acc[r] = 0.f;
#pragma unroll
    for (int t = 0; t < IN_F / (256 * 4); ++t) {
        int i4 = t * 256 + tid;
        float4 v = xrow4[i4];
        ssum += v.x + v.y + v.z + v.w;
        union { u16 h[4]; uint2 u2; } pk;
        pk.h[0] = f32_to_bf16_rne(v.x);
        pk.h[1] = f32_to_bf16_rne(v.y);
        pk.h[2] = f32_to_bf16_rne(v.z);
        pk.h[3] = f32_to_bf16_rne(v.w);
        *(uint2*)&xb[(size_t)m * IN_F + i4 * 4] = pk.u2;
#pragma unroll
        for (int r = 0; r < RANK; ++r) {
            float4 a = la4[r * (IN_F / 4) + i4];
            acc[r] = fmaf(v.x, a.x, fmaf(v.y, a.y, fmaf(v.z, a.z, fmaf(v.w, a.w, acc[r]))));
        }
    }
#pragma unroll
    for (int off = 32; off > 0; off >>= 1) {
        ssum += __shfl_down(ssum, off, 64);
#pragma unroll
        for (int r = 0; r < RANK; ++r) acc[r] += __shfl_down(acc[r], off, 64);
    }
    __shared__ float red[4][RANK + 1];
    int wv = tid >> 6, ln = tid & 63;
    if (ln == 0) {
        red[wv][0] = ssum;
#pragma unroll
        for (int r = 0; r < RANK; ++r) red[wv][1 + r] = acc[r];
    }
    __syncthreads();
    if (tid == 0) srow[m] = red[0][0] + red[1][0] + red[2][0] + red[3][0];
    if (tid < RANK)
        lxa[m * RANK + tid] = red[0][1 + tid] + red[1][1 + tid] + red[2][1 + tid] + red[3][1 + tid];
}

// ------- pack: Tw2[wq][col], wq = 2t+p covers words (4t+p, 4t+2+p) ---------
// (VERIFIED R13) One uint2 = lane's kk0 (.x) and kk1 (.y) words for iter t.
__global__ __launch_bounds__(256) void pack_kernel(
    const uint32_t* __restrict__ Tp, uint2* __restrict__ Tw2)
{
    __shared__ uint32_t s[64][NWORDS + 1];
    const int tid = threadIdx.x;
    const int col0 = blockIdx.x * 64;
#pragma unroll 8
    for (int i = 0; i < 64; ++i) {
        int idx = i * 256 + tid;
        s[idx >> 8][idx & 255] = Tp[(size_t)(col0 + (idx >> 8)) * NWORDS + (idx & 255)];
    }
    __syncthreads();
    const int c = tid & 63;
#pragma unroll 8
    for (int q = 0; q < 32; ++q) {
        int wq = q * 4 + (tid >> 6);          // 0..127
        int t = wq >> 1, p = wq & 1;
        uint2 v;
        v.x = s[c][4 * t + p];
        v.y = s[c][4 * t + 2 + p];
        Tw2[(size_t)wq * OUT_F + col0 + c] = v;
    }
}

// ---------------- init: out = bias + mu*rowsum + 2*(lxa . B^T) (VERIFIED) ---
__global__ __launch_bounds__(256) void init_kernel(
    const float* __restrict__ mu,
    const float* __restrict__ bias, const float* __restrict__ lora_B,
    const float* __restrict__ srow, const float* __restrict__ lxa,
    float* __restrict__ out)
{
    const int tid = threadIdx.x;
    const int o = blockIdx.x * 256 + tid;
    const int m0 = blockIdx.y * 32;
    float bi = bias[o];
    float muv = mu[o];
    float Br[RANK];
    const float4* b4 = (const float4*)(lora_B + (size_t)o * RANK);
#pragma unroll
    for (int r4 = 0; r4 < RANK / 4; ++r4) {
        float4 v = b4[r4];
        Br[r4 * 4 + 0] = v.x; Br[r4 * 4 + 1] = v.y;
        Br[r4 * 4 + 2] = v.z; Br[r4 * 4 + 3] = v.w;
    }
    __shared__ float ss[32];
    __shared__ float slx[32][RANK];
    if (tid < 32) ss[tid] = srow[m0 + tid];
    for (int t = tid; t < 32 * RANK; t += 256)
        slx[t >> 4][t & 15] = lxa[(m0 + (t >> 4)) * RANK + (t & 15)];
    __syncthreads();
#pragma unroll 4
    for (int mm = 0; mm < 32; ++mm) {
        float dot = 0.f;
#pragma unroll
        for (int r = 0; r < RANK; ++r) dot = fmaf(slx[mm][r], Br[r], dot);
        out[(size_t)(m0 + mm) * OUT_F + o] = bi + muv * ss[mm] + 2.0f * dot;
    }
}

// ---------------- ternary decode (VERIFIED R1-R13) ----------------
__device__ __forceinline__ short8 decode8(uint32_t h)
{
    uint32_t selA = (h & 0xFu) | ((h & 0xF0u) << 12);
    selA = (selA | (selA << 6)) & 0x03030303u;
    uint32_t h2 = h >> 8;
    uint32_t selB = (h2 & 0xFu) | ((h2 & 0xF0u) << 12);
    selB = (selB | (selB << 6)) & 0x03030303u;
    uint32_t hiA = __builtin_amdgcn_perm(0u, 0x003F00BFu, selA);
    uint32_t loA = __builtin_amdgcn_perm(0u, 0x00800080u, selA);
    uint32_t hiB = __builtin_amdgcn_perm(0u, 0x003F00BFu, selB);
    uint32_t loB = __builtin_amdgcn_perm(0u, 0x00800080u, selB);
    union { uint32_t u[4]; short8 s; } cvt;
    cvt.u[0] = __builtin_amdgcn_perm(hiA, loA, 0x05010400u);
    cvt.u[1] = __builtin_amdgcn_perm(hiA, loA, 0x07030602u);
    cvt.u[2] = __builtin_amdgcn_perm(hiB, loB, 0x05010400u);
    cvt.u[3] = __builtin_amdgcn_perm(hiB, loB, 0x07030602u);
    return cvt.s;
}

#define WAITV(N) asm volatile("s_waitcnt vmcnt(" #N ")" ::: "memory")
#define BAR    __builtin_amdgcn_s_barrier()
#define SCHED0 __builtin_amdgcn_sched_barrier(0)

struct Frags { short8 af[4][2]; };
struct BW    { uint2 w[4]; };      // per-lane B words for nt=0..3

// --- fused GEMM: 128x128 tile, 4 waves (wave-tile 64x64: mt4/nt4/kk2 =
// 32 MFMA, 8 A-reads, 8 decodes per wave-iter), 4 LDS A-bufs (64 KB),
// B in regs (Tw2, 3-slot ring, 2 ahead), split-K=4, fully unrolled NIT=16.
//
// vmcnt FIFO (units of 4 loads; loadB=4, stage=4):
//   prologue: A0 A1 A2 B0 B1 (20) -> WAITV(16) retires A0.
//   iter j (0..12): issue B(j+2), A(j+3) -> WAITV(12):
//     j=0: [A1 A2 B0 | B1 B2 A3]      retires A1,A2,B0
//     j=1: [B1 B2 | A3 B3 A4]         retires B1,B2
//     j>=2 steady: [A(j+1) B(j+1) | A(j+2) B(j+2) A(j+3)] retires A/B(j+1)
//   compute(j) needs B(j): retired at iter j-1 (j=0: this iter) -> OK
//   rdfrags(j+1) needs A(j+1): retired this iter -> OK
//   A-stage flight = 2 iters (~1900 cyc) >= HBM ~900 -> latency covered.
//   iter 13: issue B15 only -> [A14 B14 A15 B15] WAITV(12) retires A14
//   iter 14: [B14 A15 B15] WAITV(4) retires B14,A15
//   iter 15: WAITV(0) retires B15.
// Buf overwrite safety: stage((j+3)&3) at iter j overwrites frags(j-1) buf;
// last use = compute(j-1) before BAR(j-1); stage issued after BAR(j-1). OK.
__global__ __launch_bounds__(256, 2) void gemm_kernel(
    const u16* __restrict__ xb, const uint2* __restrict__ Tw2,
    const float* __restrict__ alpha, float* __restrict__ out)
{
    __shared__ __align__(16) u16 ldsA[4][BM * BK];       // 4 x 16 KB

    const int tid = threadIdx.x;
    const int lane = tid & 63;
    const int wave = tid >> 6;
    const int wm = wave >> 1, wn = wave & 1;
    const int mb = blockIdx.y * BM;
    const int nb = blockIdx.x * BN;
    const int z = blockIdx.z;

    const int bshift = ((lane >> 4) & 1) * 16;

    // A-stage: 1024 x 16B chunks; 4/thread; XOR-swizzled SOURCE, linear dest
    const u16* asrc[4];
    int adst[4];
#pragma unroll
    for (int i = 0; i < 4; ++i) {
        int q = i * 256 + tid;
        int row = q >> 3;
        int scc = (q & 7) ^ (row & 7);
        asrc[i] = xb + (size_t)(mb + row) * IN_F + z * K_PER + scc * 8;
        adst[i] = q * 8;
    }
    // B: per-lane uint2 pointers, nt=0..3; wq base = z*32 + parity
    const uint2* bptr[4];
#pragma unroll
    for (int nt = 0; nt < 4; ++nt)
        bptr[nt] = Tw2 + (size_t)(z * 32 + (lane >> 5)) * OUT_F
                       + nb + wn * 64 + nt * 16 + (lane & 15);

    int aoff[4][2];
#pragma unroll
    for (int mt = 0; mt < 4; ++mt)
#pragma unroll
        for (int kk = 0; kk < 2; ++kk) {
            int r = wm * 64 + mt * 16 + (lane & 15);
            int sc = kk * 4 + (lane >> 4);
            aoff[mt][kk] = (r * 8 + (sc ^ (r & 7))) * 8;
        }

    floatx4 acc[4][4] = {};

    auto stage = [&](int buf, int jt) {
#pragma unroll
        for (int i = 0; i < 4; ++i) {
            __builtin_amdgcn_global_load_lds(
                (const __attribute__((address_space(1))) void*)(asrc[i] + jt * BK),
                (__attribute__((address_space(3))) void*)(&ldsA[buf][adst[i]]),
                16, 0, 0);
        }
    };
    auto loadB = [&](BW& b, int jt) {
#pragma unroll
        for (int nt = 0; nt < 4; ++nt)
            b.w[nt] = bptr[nt][(size_t)(2 * jt) * OUT_F];
    };
    auto rdfrags = [&](int buf, Frags& F) {
#pragma unroll
        for (int mt = 0; mt < 4; ++mt)
#pragma unroll
            for (int kk = 0; kk < 2; ++kk)
                F.af[mt][kk] = *(const short8*)&ldsA[buf][aoff[mt][kk]];
    };
    auto compute = [&](Frags& F, BW& b) {
        __builtin_amdgcn_s_setprio(1);
#pragma unroll
        for (int kk = 0; kk < 2; ++kk) {
#pragma unroll
            for (int nt = 0; nt < 4; ++nt) {
                uint32_t w = kk ? b.w[nt].y : b.w[nt].x;
                short8 bf = decode8((w >> bshift) & 0xFFFFu);
#pragma unroll
                for (int mt = 0; mt < 4; ++mt)
                    acc[mt][nt] = __builtin_amdgcn_mfma_f32_16x16x32_bf16(
                        F.af[mt][kk], bf, acc[mt][nt], 0, 0, 0);
            }
        }
        __builtin_amdgcn_s_setprio(0);
    };

    Frags f0, f1;
    BW bw[3];

    // prologue
    stage(0, 0); stage(1, 1); stage(2, 2);
    loadB(bw[0], 0); loadB(bw[1], 1);
    WAITV(16); BAR;
    rdfrags(0, f0); SCHED0;

    // steady j = 0..12 (fully unrolled; all indices compile-time)
#pragma unroll
    for (int j = 0; j <= 12; ++j) {
        loadB(bw[(j + 2) % 3], j + 2);
        stage((j + 3) & 3, j + 3); SCHED0;
        WAITV(12);
        if ((j & 1) == 0) { compute(f0, bw[j % 3]); } else { compute(f1, bw[j % 3]); }
        BAR;
        if ((j & 1) == 0) { rdfrags((j + 1) & 3, f1); } else { rdfrags((j + 1) & 3, f0); }
        SCHED0;
    }
    // iter 13
    loadB(bw[0], 15); SCHED0;
    WAITV(12); compute(f1, bw[1]); BAR; rdfrags(2, f0); SCHED0;
    // iter 14
    WAITV(4); compute(f0, bw[2]); BAR; rdfrags(3, f1); SCHED0;
    // iter 15
    WAITV(0); compute(f1, bw[0]);

    // ---- epilogue: atomicAdd alpha*acc onto init-kernel affine base ----
    const int o0 = nb + wn * 64 + (lane & 15);
    const int m0 = mb + wm * 64 + ((lane >> 4) * 4);
    float al[4];
#pragma unroll
    for (int nt = 0; nt < 4; ++nt) al[nt] = alpha[o0 + nt * 16];
#pragma unroll
    for (int mt = 0; mt < 4; ++mt) {
#pragma unroll
        for (int rg = 0; rg < 4; ++rg) {
            int m = m0 + mt * 16 + rg;
#pragma unroll
            for (int nt = 0; nt < 4; ++nt)
                atomicAdd(&out[(size_t)m * OUT_F + o0 + nt * 16],
                          al[nt] * acc[mt][nt][rg]);
        }
    }
}

extern "C" void kernel_launch(void* const* d_in, const int* in_sizes, int n_in,
                              void* d_out, int out_size, void* d_ws, size_t ws_size,
                              hipStream_t stream)
{
    const float* x = (const float*)d_in[0];
    const uint32_t* Tp = (const uint32_t*)d_in[1];
    const float* alpha = (const float*)d_in[2];
    const float* mu = (const float*)d_in[3];
    const float* bias = (const float*)d_in[4];
    const float* lora_A = (const float*)d_in[5];
    const float* lora_B = (const float*)d_in[6];
    float* out = (float*)d_out;

    u16* xb = (u16*)d_ws;                                    // 2 MB
    float* srow = (float*)((char*)d_ws + (size_t)M_ROWS * IN_F * 2);
    float* lxa = (float*)((char*)d_ws + (size_t)M_ROWS * IN_F * 2 + 4096);
    uint2* Tw2 = (uint2*)((char*)d_ws + (4u << 20));         // 11.3 MB at +4MB

    prep_kernel<<<dim3(M_ROWS), dim3(256), 0, stream>>>(x, lora_A, xb, srow, lxa);
    pack_kernel<<<dim3(OUT_F / 64), dim3(256), 0, stream>>>(Tp, Tw2);
    init_kernel<<<dim3(OUT_F / 256, M_ROWS / 32), dim3(256), 0, stream>>>(
        mu, bias, lora_B, srow, lxa, out);
    gemm_kernel<<<dim3(OUT_F / BN, M_ROWS / BM, KSPLIT), dim3(256), 0, stream>>>(
        xb, Tw2, alpha, out);
}